// Round 7
// baseline (196.548 us; speedup 1.0000x reference)
//
#include <hip/hip_runtime.h>
#include <math.h>

#define B_ 4
#define N_ 2048
#define C_ 64
#define K_ 32
#define BN_ (B_ * N_)  // 8192

// ws float layout (all regions rewritten every launch before being read):
// [0]            WS_NLL   nll accumulator (zeroed by k_main block 0)
// [8]            WS_DONE  unsigned done-counter for last-block final (zeroed)
// [64, 8256)     MEANS    B*K*C, count-divide fused (k_main cluster blocks)
// [8320, 10368)  APART    1024 * {sum, cnt} (k_main anchor blocks)
#define WS_NLL 0
#define WS_DONE 8
#define WS_MEANS 64
#define WS_APART 8320

__device__ __forceinline__ void pair4(float sx, float sy, float4 xs, float4 ys,
                                      int4 m, float& acc, int& cnt) {
  float dx, dy, d2, v;
  dx = sx - xs.x; dy = sy - ys.x; d2 = dx * dx + dy * dy;
  v = 1.0f - __expf(d2 * -0.1f);
  if (m.x == 1) { acc += v; cnt += 1; }
  dx = sx - xs.y; dy = sy - ys.y; d2 = dx * dx + dy * dy;
  v = 1.0f - __expf(d2 * -0.1f);
  if (m.y == 1) { acc += v; cnt += 1; }
  dx = sx - xs.z; dy = sy - ys.z; d2 = dx * dx + dy * dy;
  v = 1.0f - __expf(d2 * -0.1f);
  if (m.z == 1) { acc += v; cnt += 1; }
  dx = sx - xs.w; dy = sy - ys.w; d2 = dx * dx + dy * dy;
  v = 1.0f - __expf(d2 * -0.1f);
  if (m.w == 1) { acc += v; cnt += 1; }
}

// 1152 blocks x 256, two block-uniform roles (unchanged from R6 — passed,
// <41 µs): blocks [0,128) cluster means via ballot-scan; blocks [128,1152)
// streaming anchor with self-staged coords. Block 0 zeroes NLL/DONE.
__global__ __launch_bounds__(256) void k_main(
    const float* __restrict__ emb, const float* __restrict__ absc,
    const float* __restrict__ contr, const int* __restrict__ labels,
    const int* __restrict__ mask, float* __restrict__ ws) {
  __shared__ union {
    struct { float sx[N_]; float sy[N_]; } a;                    // 16 KB
    struct { int lab[N_]; float lsum[4][64]; float lcnt[4]; } c; // 9.3 KB
  } sm;
  __shared__ float red[8];
  int t = threadIdx.x, lane = t & 63, w = t >> 6;
  int bid = blockIdx.x;
  if (bid < 128) {
    int b = bid >> 5, k = bid & 31;
    if (bid == 0 && t == 0) {
      ws[WS_NLL] = 0.0f;
      ((unsigned*)ws)[WS_DONE] = 0u;
    }
    const int4* lab4 = (const int4*)(labels + b * N_);
    int4* l4 = (int4*)sm.c.lab;
    l4[t] = lab4[t];
    l4[t + 256] = lab4[t + 256];
    __syncthreads();
    float acc = 0.0f, cnt = 0.0f;
    for (int g0 = w * 512; g0 < w * 512 + 512; g0 += 64) {
      unsigned long long mb = __ballot(sm.c.lab[g0 + lane] == k);
      while (mb) {
        int bit = __ffsll(mb) - 1;
        mb &= mb - 1;
        int r = g0 + bit;
        float x = contr[(size_t)(b * N_ + r) * C_ + lane];
        float ss = x * x;
#pragma unroll
        for (int off = 32; off > 0; off >>= 1) ss += __shfl_xor(ss, off);
        acc += x * (1.0f / fmaxf(sqrtf(ss), 1e-12f));
        cnt += 1.0f;
      }
    }
    sm.c.lsum[w][lane] = acc;
    if (lane == 0) sm.c.lcnt[w] = cnt;
    __syncthreads();
    if (t < 64) {
      float s = sm.c.lsum[0][t] + sm.c.lsum[1][t] + sm.c.lsum[2][t] + sm.c.lsum[3][t];
      float c = sm.c.lcnt[0] + sm.c.lcnt[1] + sm.c.lcnt[2] + sm.c.lcnt[3];
      ws[WS_MEANS + (b * K_ + k) * C_ + t] = s / fmaxf(c, 1.0f);
    }
  } else {
    int aid = bid - 128;             // [0,1024)
    int b = aid >> 8;                // 256 blocks per batch
    int flat = (aid & 255) * 256 + t;  // [0, 65536) int4 slot within batch
    const float4* e4 = (const float4*)(emb + b * N_ * 2);
    const float4* a4 = (const float4*)(absc + b * N_ * 2);
    for (int i = t; i < N_ / 2; i += 256) {
      float4 ev = e4[i], av = a4[i];
      sm.a.sx[2 * i]     = ev.x + av.x;
      sm.a.sy[2 * i]     = ev.y + av.y;
      sm.a.sx[2 * i + 1] = ev.z + av.z;
      sm.a.sy[2 * i + 1] = ev.w + av.w;
    }
    __syncthreads();
    int cg = flat & 511;             // fixed float4 column group
    float4 xs = ((const float4*)sm.a.sx)[cg];
    float4 ys = ((const float4*)sm.a.sy)[cg];
    const int4* m4 = (const int4*)mask + (size_t)b * (N_ * (size_t)N_ / 4);
    float acc = 0.0f;
    int cnt = 0;
#pragma unroll
    for (int it = 0; it < 16; ++it) {
      int idx = flat + it * 65536;
      int4 m = m4[idx];
      int row = idx >> 9;            // block-uniform -> LDS broadcast
      pair4(sm.a.sx[row], sm.a.sy[row], xs, ys, m, acc, cnt);
    }
    float cntf = (float)cnt;
#pragma unroll
    for (int off = 32; off > 0; off >>= 1) {
      acc += __shfl_xor(acc, off);
      cntf += __shfl_xor(cntf, off);
    }
    if (lane == 0) { red[w * 2] = acc; red[w * 2 + 1] = cntf; }
    __syncthreads();
    if (t == 0) {
      ws[WS_APART + aid * 2 + 0] = red[0] + red[2] + red[4] + red[6];
      ws[WS_APART + aid * 2 + 1] = red[1] + red[3] + red[5] + red[7];
    }
  }
}

// 512 blocks x 128 (2 waves). Block = 16 rows; lane = logit column (wave w
// -> cols [w*64, w*64+64)). R6's version was latency-bound (42.6 µs even
// fully cached: 32 serial rows x (64-deep FMA chain + 2 shuffle reductions)).
// Fixes: (1) 16 rows, 2x blocks; (2) all 16 dots batched into acc[16] —
// independent chains, ILP hides LDS+FMA latency; (3) NO max-subtraction:
// |logit| <= 1 (cosine vs mean-of-unit-vectors), exp cannot overflow ->
// one sum-reduction per row, no rescale; (4) norms by 16 parallel threads.
__global__ __launch_bounds__(128) void k_logits_final(
    const float* __restrict__ contr, const int* __restrict__ labels,
    float* __restrict__ ws, float* __restrict__ out) {
  __shared__ float lc[16 * C_];    // 4 KB raw rows
  __shared__ float invr[16];
  __shared__ float lsv[2][16], ltl[16];
  __shared__ float fred[4];
  __shared__ int lastf;
  int t = threadIdx.x, lane = t & 63, w = t >> 6;
  int r0 = blockIdx.x * 16;
  int j = w * 64 + lane;
  const float4* mean4 = (const float4*)(ws + WS_MEANS);
  float4 mk[16];
#pragma unroll
  for (int q = 0; q < 16; ++q) mk[q] = mean4[j * 16 + q];
  const float4* c4 = (const float4*)(contr + (size_t)r0 * C_);
  float4* lc4 = (float4*)lc;
  lc4[t] = c4[t];
  lc4[t + 128] = c4[t + 128];
  __syncthreads();
  if (t < 16) {                    // 16 parallel per-row norms, no shuffles
    float ss = 0.0f;
#pragma unroll
    for (int q = 0; q < 16; ++q) {
      float4 v = lc4[t * 16 + q];
      ss += v.x * v.x + v.y * v.y + v.z * v.z + v.w * v.w;
    }
    invr[t] = 1.0f / fmaxf(sqrtf(ss), 1e-12f);
  }
  __syncthreads();
  float acc[16];
#pragma unroll
  for (int r = 0; r < 16; ++r) {   // 16 independent dot chains (ILP)
    const float4* cr = lc4 + r * 16;
    float a = 0.0f;
#pragma unroll
    for (int q = 0; q < 16; ++q) {
      float4 cv = cr[q];
      a += cv.x * mk[q].x + cv.y * mk[q].y + cv.z * mk[q].z + cv.w * mk[q].w;
    }
    acc[r] = a;
  }
#pragma unroll
  for (int r = 0; r < 16; ++r) {   // 16 independent sum-reductions (no max)
    float l = acc[r] * invr[r];
    float s = __expf(l);
#pragma unroll
    for (int off = 32; off > 0; off >>= 1) s += __shfl_xor(s, off);
    int tgt = labels[r0 + r];      // [0,32): wave 0, lane==col==tgt
    float tl = __shfl(l, tgt);
    if (lane == 0) {
      lsv[w][r] = s;
      if (w == 0) ltl[r] = tl;
    }
  }
  __syncthreads();
  if (t < 16) {
    float nll = __logf(lsv[0][t] + lsv[1][t]) - ltl[t];
#pragma unroll
    for (int off = 8; off > 0; off >>= 1) nll += __shfl_xor(nll, off);
    if (t == 0) atomicAdd(&ws[WS_NLL], nll);
  }
  // ---- last-block final combine (release/acquire via done-counter) ----
  __syncthreads();
  if (t == 0) {
    __threadfence();               // release: my nll add visible
    unsigned v = atomicAdd(&((unsigned*)ws)[WS_DONE], 1u);
    lastf = (v == 511u);
  }
  __syncthreads();
  if (lastf) {
    __threadfence();               // acquire: all blocks' adds visible
    float a = 0.0f, c = 0.0f;
    for (int i = t; i < 1024; i += 128) {
      a += ws[WS_APART + i * 2 + 0];
      c += ws[WS_APART + i * 2 + 1];
    }
#pragma unroll
    for (int off = 32; off > 0; off >>= 1) {
      a += __shfl_xor(a, off);
      c += __shfl_xor(c, off);
    }
    if (lane == 0) { fred[w * 2] = a; fred[w * 2 + 1] = c; }
    __syncthreads();
    if (t == 0) {
      float at = fred[0] + fred[2];
      float ct = fred[1] + fred[3];
      out[0] = at / ct + 10.0f * ws[WS_NLL] * (1.0f / (float)BN_);
    }
  }
}

extern "C" void kernel_launch(void* const* d_in, const int* in_sizes, int n_in,
                              void* d_out, int out_size, void* d_ws, size_t ws_size,
                              hipStream_t stream) {
  const float* emb    = (const float*)d_in[0];
  const float* contr  = (const float*)d_in[1];
  const float* absc   = (const float*)d_in[2];
  const int*   mask   = (const int*)d_in[3];
  const int*   labels = (const int*)d_in[4];
  float* ws  = (float*)d_ws;
  float* out = (float*)d_out;

  k_main<<<128 + 1024, 256, 0, stream>>>(emb, absc, contr, labels, mask, ws);
  k_logits_final<<<512, 128, 0, stream>>>(contr, labels, ws, out);
}

// Round 8
// 140.368 us; speedup vs baseline: 1.4002x; 1.4002x over previous
//
#include <hip/hip_runtime.h>
#include <math.h>

#define B_ 4
#define N_ 2048
#define C_ 64
#define K_ 32
#define BN_ (B_ * N_)  // 8192

// ws float layout (all regions rewritten every launch before being read):
// [0]            WS_NLL   nll accumulator (zeroed by k_main block 0)
// [8]            WS_DONE  unsigned done-counter for last-block final (zeroed)
// [64, 8256)     MEANS    B*K*C, count-divide fused (k_main cluster blocks)
// [8320, 10368)  APART    1024 * {sum, cnt} (k_main anchor blocks)
#define WS_NLL 0
#define WS_DONE 8
#define WS_MEANS 64
#define WS_APART 8320

__device__ __forceinline__ void pair4(float sx, float sy, float4 xs, float4 ys,
                                      int4 m, float& acc, int& cnt) {
  float dx, dy, d2, v;
  dx = sx - xs.x; dy = sy - ys.x; d2 = dx * dx + dy * dy;
  v = 1.0f - __expf(d2 * -0.1f);
  if (m.x == 1) { acc += v; cnt += 1; }
  dx = sx - xs.y; dy = sy - ys.y; d2 = dx * dx + dy * dy;
  v = 1.0f - __expf(d2 * -0.1f);
  if (m.y == 1) { acc += v; cnt += 1; }
  dx = sx - xs.z; dy = sy - ys.z; d2 = dx * dx + dy * dy;
  v = 1.0f - __expf(d2 * -0.1f);
  if (m.z == 1) { acc += v; cnt += 1; }
  dx = sx - xs.w; dy = sy - ys.w; d2 = dx * dx + dy * dy;
  v = 1.0f - __expf(d2 * -0.1f);
  if (m.w == 1) { acc += v; cnt += 1; }
}

// 1152 blocks x 256, two block-uniform roles (unchanged since R6 — <41 µs):
// blocks [0,128) cluster means via ballot-scan; blocks [128,1152) streaming
// anchor with self-staged coords. Block 0 zeroes NLL/DONE.
__global__ __launch_bounds__(256) void k_main(
    const float* __restrict__ emb, const float* __restrict__ absc,
    const float* __restrict__ contr, const int* __restrict__ labels,
    const int* __restrict__ mask, float* __restrict__ ws) {
  __shared__ union {
    struct { float sx[N_]; float sy[N_]; } a;                    // 16 KB
    struct { int lab[N_]; float lsum[4][64]; float lcnt[4]; } c; // 9.3 KB
  } sm;
  __shared__ float red[8];
  int t = threadIdx.x, lane = t & 63, w = t >> 6;
  int bid = blockIdx.x;
  if (bid < 128) {
    int b = bid >> 5, k = bid & 31;
    if (bid == 0 && t == 0) {
      ws[WS_NLL] = 0.0f;
      ((unsigned*)ws)[WS_DONE] = 0u;
    }
    const int4* lab4 = (const int4*)(labels + b * N_);
    int4* l4 = (int4*)sm.c.lab;
    l4[t] = lab4[t];
    l4[t + 256] = lab4[t + 256];
    __syncthreads();
    float acc = 0.0f, cnt = 0.0f;
    for (int g0 = w * 512; g0 < w * 512 + 512; g0 += 64) {
      unsigned long long mb = __ballot(sm.c.lab[g0 + lane] == k);
      while (mb) {
        int bit = __ffsll(mb) - 1;
        mb &= mb - 1;
        int r = g0 + bit;
        float x = contr[(size_t)(b * N_ + r) * C_ + lane];
        float ss = x * x;
#pragma unroll
        for (int off = 32; off > 0; off >>= 1) ss += __shfl_xor(ss, off);
        acc += x * (1.0f / fmaxf(sqrtf(ss), 1e-12f));
        cnt += 1.0f;
      }
    }
    sm.c.lsum[w][lane] = acc;
    if (lane == 0) sm.c.lcnt[w] = cnt;
    __syncthreads();
    if (t < 64) {
      float s = sm.c.lsum[0][t] + sm.c.lsum[1][t] + sm.c.lsum[2][t] + sm.c.lsum[3][t];
      float c = sm.c.lcnt[0] + sm.c.lcnt[1] + sm.c.lcnt[2] + sm.c.lcnt[3];
      ws[WS_MEANS + (b * K_ + k) * C_ + t] = s / fmaxf(c, 1.0f);
    }
  } else {
    int aid = bid - 128;             // [0,1024)
    int b = aid >> 8;                // 256 blocks per batch
    int flat = (aid & 255) * 256 + t;  // [0, 65536) int4 slot within batch
    const float4* e4 = (const float4*)(emb + b * N_ * 2);
    const float4* a4 = (const float4*)(absc + b * N_ * 2);
    for (int i = t; i < N_ / 2; i += 256) {
      float4 ev = e4[i], av = a4[i];
      sm.a.sx[2 * i]     = ev.x + av.x;
      sm.a.sy[2 * i]     = ev.y + av.y;
      sm.a.sx[2 * i + 1] = ev.z + av.z;
      sm.a.sy[2 * i + 1] = ev.w + av.w;
    }
    __syncthreads();
    int cg = flat & 511;             // fixed float4 column group
    float4 xs = ((const float4*)sm.a.sx)[cg];
    float4 ys = ((const float4*)sm.a.sy)[cg];
    const int4* m4 = (const int4*)mask + (size_t)b * (N_ * (size_t)N_ / 4);
    float acc = 0.0f;
    int cnt = 0;
#pragma unroll
    for (int it = 0; it < 16; ++it) {
      int idx = flat + it * 65536;
      int4 m = m4[idx];
      int row = idx >> 9;            // block-uniform -> LDS broadcast
      pair4(sm.a.sx[row], sm.a.sy[row], xs, ys, m, acc, cnt);
    }
    float cntf = (float)cnt;
#pragma unroll
    for (int off = 32; off > 0; off >>= 1) {
      acc += __shfl_xor(acc, off);
      cntf += __shfl_xor(cntf, off);
    }
    if (lane == 0) { red[w * 2] = acc; red[w * 2 + 1] = cntf; }
    __syncthreads();
    if (t == 0) {
      ws[WS_APART + aid * 2 + 0] = red[0] + red[2] + red[4] + red[6];
      ws[WS_APART + aid * 2 + 1] = red[1] + red[3] + red[5] + red[7];
    }
  }
}

// 512 blocks x 128 (2 waves). Block = 16 rows; lane = logit column (wave w
// -> cols [w*64, w*64+64)).
// R6 (VGPR=48): compiler re-loaded means per row -> 42 µs latency-bound.
// R7 (ILP=16): VGPR=256 + 200 MB scratch spill -> 83 µs.
// R8: ILP=4 — outer row loop `#pragma unroll 1` (4 iters, blocks hoisting),
// inner 16-quad loop unrolled over 4 rows vs register-resident mk[16].
// Live set ~100 VGPR: no spill, means stay resident, 4 independent chains.
// No max-subtraction (|logit|<=1: cosine vs mean of unit vectors). Last
// block (done-counter) reduces anchor partials and writes the scalar.
__global__ __launch_bounds__(128) void k_logits_final(
    const float* __restrict__ contr, const int* __restrict__ labels,
    float* __restrict__ ws, float* __restrict__ out) {
  __shared__ float lc[16 * C_];    // 4 KB raw rows
  __shared__ float invr[16];
  __shared__ float lsv[2][16], ltl[16];
  __shared__ float fred[4];
  __shared__ int lastf;
  int t = threadIdx.x, lane = t & 63, w = t >> 6;
  int r0 = blockIdx.x * 16;
  int j = w * 64 + lane;
  const float4* mean4 = (const float4*)(ws + WS_MEANS);
  float4 mk[16];
#pragma unroll
  for (int q = 0; q < 16; ++q) mk[q] = mean4[j * 16 + q];
  const float4* c4 = (const float4*)(contr + (size_t)r0 * C_);
  float4* lc4 = (float4*)lc;
  lc4[t] = c4[t];
  lc4[t + 128] = c4[t + 128];
  __syncthreads();
  if (t < 16) {                    // 16 parallel per-row norms
    float ss = 0.0f;
#pragma unroll
    for (int q = 0; q < 16; ++q) {
      float4 v = lc4[t * 16 + q];
      ss += v.x * v.x + v.y * v.y + v.z * v.z + v.w * v.w;
    }
    invr[t] = 1.0f / fmaxf(sqrtf(ss), 1e-12f);
  }
  __syncthreads();
#pragma unroll 1
  for (int rg = 0; rg < 4; ++rg) { // 4 rows at a time: ILP without spill
    const float4* cr = lc4 + rg * 64;
    float a0 = 0.0f, a1 = 0.0f, a2 = 0.0f, a3 = 0.0f;
#pragma unroll
    for (int q = 0; q < 16; ++q) {
      float4 m = mk[q];
      float4 c0 = cr[q], c1 = cr[16 + q], c2 = cr[32 + q], c3 = cr[48 + q];
      a0 += c0.x * m.x + c0.y * m.y + c0.z * m.z + c0.w * m.w;
      a1 += c1.x * m.x + c1.y * m.y + c1.z * m.z + c1.w * m.w;
      a2 += c2.x * m.x + c2.y * m.y + c2.z * m.z + c2.w * m.w;
      a3 += c3.x * m.x + c3.y * m.y + c3.z * m.z + c3.w * m.w;
    }
    int rb = rg * 4;
    float l0 = a0 * invr[rb + 0];
    float l1 = a1 * invr[rb + 1];
    float l2 = a2 * invr[rb + 2];
    float l3 = a3 * invr[rb + 3];
    float s0 = __expf(l0), s1 = __expf(l1), s2 = __expf(l2), s3 = __expf(l3);
#pragma unroll
    for (int off = 32; off > 0; off >>= 1) {  // 4 interleaved reductions
      s0 += __shfl_xor(s0, off);
      s1 += __shfl_xor(s1, off);
      s2 += __shfl_xor(s2, off);
      s3 += __shfl_xor(s3, off);
    }
    int tg0 = labels[r0 + rb + 0], tg1 = labels[r0 + rb + 1];
    int tg2 = labels[r0 + rb + 2], tg3 = labels[r0 + rb + 3];
    float t0 = __shfl(l0, tg0), t1 = __shfl(l1, tg1);
    float t2 = __shfl(l2, tg2), t3 = __shfl(l3, tg3);
    if (lane == 0) {
      lsv[w][rb + 0] = s0; lsv[w][rb + 1] = s1;
      lsv[w][rb + 2] = s2; lsv[w][rb + 3] = s3;
      if (w == 0) { ltl[rb] = t0; ltl[rb + 1] = t1; ltl[rb + 2] = t2; ltl[rb + 3] = t3; }
    }
  }
  __syncthreads();
  if (t < 16) {
    float nll = __logf(lsv[0][t] + lsv[1][t]) - ltl[t];
#pragma unroll
    for (int off = 8; off > 0; off >>= 1) nll += __shfl_xor(nll, off);
    if (t == 0) atomicAdd(&ws[WS_NLL], nll);
  }
  // ---- last-block final combine (release/acquire via done-counter) ----
  __syncthreads();
  if (t == 0) {
    __threadfence();               // release: my nll add visible
    unsigned v = atomicAdd(&((unsigned*)ws)[WS_DONE], 1u);
    lastf = (v == 511u);
  }
  __syncthreads();
  if (lastf) {
    __threadfence();               // acquire: all blocks' adds visible
    float a = 0.0f, c = 0.0f;
    for (int i = t; i < 1024; i += 128) {
      a += ws[WS_APART + i * 2 + 0];
      c += ws[WS_APART + i * 2 + 1];
    }
#pragma unroll
    for (int off = 32; off > 0; off >>= 1) {
      a += __shfl_xor(a, off);
      c += __shfl_xor(c, off);
    }
    if (lane == 0) { fred[w * 2] = a; fred[w * 2 + 1] = c; }
    __syncthreads();
    if (t == 0) {
      float at = fred[0] + fred[2];
      float ct = fred[1] + fred[3];
      out[0] = at / ct + 10.0f * ws[WS_NLL] * (1.0f / (float)BN_);
    }
  }
}

extern "C" void kernel_launch(void* const* d_in, const int* in_sizes, int n_in,
                              void* d_out, int out_size, void* d_ws, size_t ws_size,
                              hipStream_t stream) {
  const float* emb    = (const float*)d_in[0];
  const float* contr  = (const float*)d_in[1];
  const float* absc   = (const float*)d_in[2];
  const int*   mask   = (const int*)d_in[3];
  const int*   labels = (const int*)d_in[4];
  float* ws  = (float*)d_ws;
  float* out = (float*)d_out;

  k_main<<<128 + 1024, 256, 0, stream>>>(emb, absc, contr, labels, mask, ws);
  k_logits_final<<<512, 128, 0, stream>>>(contr, labels, ws, out);
}

// Round 9
// 140.139 us; speedup vs baseline: 1.4025x; 1.0016x over previous
//
#include <hip/hip_runtime.h>
#include <math.h>

#define B_ 4
#define N_ 2048
#define C_ 64
#define K_ 32
#define BN_ (B_ * N_)  // 8192

// ws float layout (all regions rewritten every launch before being read):
// [0]            WS_NLL   nll accumulator (zeroed by k_main block 0)
// [8]            WS_DONE  unsigned done-counter for last-block final (zeroed)
// [64, 8256)     MEANS    B*K*C, count-divide fused (k_main cluster blocks)
// [8320, 10368)  APART    1024 * {sum, cnt} (k_main anchor blocks)
#define WS_NLL 0
#define WS_DONE 8
#define WS_MEANS 64
#define WS_APART 8320

// Lean pair step: mask values are {0,1} (randint(0,2)), so (m==1) == m and
// sum(m*(1-e)) = cnt - sum(m*e). 9 VALU/pair: sub,sub,mul,fma,mul,exp,cvt,
// fma,int-add (vs ~12 with cndmask form).
__device__ __forceinline__ void proc4(int4 m, float rx, float ry,
                                      float4 xs, float4 ys,
                                      float& S, int& cnt) {
  float dx, dy, d2;
  dx = rx - xs.x; dy = ry - ys.x; d2 = dx * dx + dy * dy;
  S += (float)m.x * __expf(d2 * -0.1f); cnt += m.x;
  dx = rx - xs.y; dy = ry - ys.y; d2 = dx * dx + dy * dy;
  S += (float)m.y * __expf(d2 * -0.1f); cnt += m.y;
  dx = rx - xs.z; dy = ry - ys.z; d2 = dx * dx + dy * dy;
  S += (float)m.z * __expf(d2 * -0.1f); cnt += m.z;
  dx = rx - xs.w; dy = ry - ys.w; d2 = dx * dx + dy * dy;
  S += (float)m.w * __expf(d2 * -0.1f); cnt += m.w;
}

// 1152 blocks x 256, two block-uniform roles:
//  blocks [0,128):    cluster means via ballot-scan (unchanged since R6).
//  blocks [128,1152): streaming anchor, software-pipelined: 16 int4/thread in
//    4 groups of 4; next group's loads issued BEFORE processing the current
//    (unroll 1 + peeled tail -> rolled loop, ~70 VGPR, no R7-style spill).
//    aid8=aid&255: flat0 = aid8*256+t -> row base rb0 = aid8>>1 is
//    block-uniform; column group cg=(aid8&1)*256+t is thread-fixed (xs/ys
//    read once); slot s adds 128 rows. Coords staged in LDS per block.
__global__ __launch_bounds__(256) void k_main(
    const float* __restrict__ emb, const float* __restrict__ absc,
    const float* __restrict__ contr, const int* __restrict__ labels,
    const int* __restrict__ mask, float* __restrict__ ws) {
  __shared__ union {
    struct { float sx[N_]; float sy[N_]; } a;                    // 16 KB
    struct { int lab[N_]; float lsum[4][64]; float lcnt[4]; } c; // 9.3 KB
  } sm;
  __shared__ float red[8];
  int t = threadIdx.x, lane = t & 63, w = t >> 6;
  int bid = blockIdx.x;
  if (bid < 128) {
    int b = bid >> 5, k = bid & 31;
    if (bid == 0 && t == 0) {
      ws[WS_NLL] = 0.0f;
      ((unsigned*)ws)[WS_DONE] = 0u;
    }
    const int4* lab4 = (const int4*)(labels + b * N_);
    int4* l4 = (int4*)sm.c.lab;
    l4[t] = lab4[t];
    l4[t + 256] = lab4[t + 256];
    __syncthreads();
    float acc = 0.0f, cnt = 0.0f;
    for (int g0 = w * 512; g0 < w * 512 + 512; g0 += 64) {
      unsigned long long mb = __ballot(sm.c.lab[g0 + lane] == k);
      while (mb) {
        int bit = __ffsll(mb) - 1;
        mb &= mb - 1;
        int r = g0 + bit;
        float x = contr[(size_t)(b * N_ + r) * C_ + lane];
        float ss = x * x;
#pragma unroll
        for (int off = 32; off > 0; off >>= 1) ss += __shfl_xor(ss, off);
        acc += x * (1.0f / fmaxf(sqrtf(ss), 1e-12f));
        cnt += 1.0f;
      }
    }
    sm.c.lsum[w][lane] = acc;
    if (lane == 0) sm.c.lcnt[w] = cnt;
    __syncthreads();
    if (t < 64) {
      float s = sm.c.lsum[0][t] + sm.c.lsum[1][t] + sm.c.lsum[2][t] + sm.c.lsum[3][t];
      float c = sm.c.lcnt[0] + sm.c.lcnt[1] + sm.c.lcnt[2] + sm.c.lcnt[3];
      ws[WS_MEANS + (b * K_ + k) * C_ + t] = s / fmaxf(c, 1.0f);
    }
  } else {
    int aid = bid - 128;               // [0,1024)
    int b = aid >> 8;                  // 256 blocks per batch
    int aid8 = aid & 255;
    const float4* e4 = (const float4*)(emb + b * N_ * 2);
    const float4* a4 = (const float4*)(absc + b * N_ * 2);
    for (int i = t; i < N_ / 2; i += 256) {
      float4 ev = e4[i], av = a4[i];
      sm.a.sx[2 * i]     = ev.x + av.x;
      sm.a.sy[2 * i]     = ev.y + av.y;
      sm.a.sx[2 * i + 1] = ev.z + av.z;
      sm.a.sy[2 * i + 1] = ev.w + av.w;
    }
    __syncthreads();
    int cg = (aid8 & 1) * 256 + t;     // fixed float4 column group [0,512)
    float4 xs = ((const float4*)sm.a.sx)[cg];
    float4 ys = ((const float4*)sm.a.sy)[cg];
    int rb0 = aid8 >> 1;               // block-uniform base row
    const int4* mp = (const int4*)mask + (size_t)b * (N_ * (size_t)N_ / 4)
                     + aid8 * 256 + t; // slot s at mp[s*65536], row rb0+s*128
    int4 c0 = mp[0], c1 = mp[65536], c2 = mp[131072], c3 = mp[196608];
    float S = 0.0f;
    int cnt = 0;
#pragma unroll 1
    for (int g = 0; g < 3; ++g) {
      const int4* np = mp + (size_t)(g + 1) * 262144;
      int4 n0 = np[0], n1 = np[65536], n2 = np[131072], n3 = np[196608];
      int rr = rb0 + g * 512;
      proc4(c0, sm.a.sx[rr],       sm.a.sy[rr],       xs, ys, S, cnt);
      proc4(c1, sm.a.sx[rr + 128], sm.a.sy[rr + 128], xs, ys, S, cnt);
      proc4(c2, sm.a.sx[rr + 256], sm.a.sy[rr + 256], xs, ys, S, cnt);
      proc4(c3, sm.a.sx[rr + 384], sm.a.sy[rr + 384], xs, ys, S, cnt);
      c0 = n0; c1 = n1; c2 = n2; c3 = n3;
    }
    int rr = rb0 + 3 * 512;
    proc4(c0, sm.a.sx[rr],       sm.a.sy[rr],       xs, ys, S, cnt);
    proc4(c1, sm.a.sx[rr + 128], sm.a.sy[rr + 128], xs, ys, S, cnt);
    proc4(c2, sm.a.sx[rr + 256], sm.a.sy[rr + 256], xs, ys, S, cnt);
    proc4(c3, sm.a.sx[rr + 384], sm.a.sy[rr + 384], xs, ys, S, cnt);
    float cntf = (float)cnt;
    float acc = cntf - S;              // sum m*(1-e) = cnt - sum(m*e)
#pragma unroll
    for (int off = 32; off > 0; off >>= 1) {
      acc += __shfl_xor(acc, off);
      cntf += __shfl_xor(cntf, off);
    }
    if (lane == 0) { red[w * 2] = acc; red[w * 2 + 1] = cntf; }
    __syncthreads();
    if (t == 0) {
      ws[WS_APART + aid * 2 + 0] = red[0] + red[2] + red[4] + red[6];
      ws[WS_APART + aid * 2 + 1] = red[1] + red[3] + red[5] + red[7];
    }
  }
}

// 512 blocks x 128 (2 waves). Block = 16 rows; lane = logit column (wave w
// -> cols [w*64, w*64+64)). ILP=4 row groups vs register-resident mk[16]
// (R8 structure — no spill, means resident). No max-subtraction (|logit|<=1:
// cosine vs mean of unit vectors). Last block (done-counter) reduces anchor
// partials and writes the final scalar.
__global__ __launch_bounds__(128) void k_logits_final(
    const float* __restrict__ contr, const int* __restrict__ labels,
    float* __restrict__ ws, float* __restrict__ out) {
  __shared__ float lc[16 * C_];    // 4 KB raw rows
  __shared__ float invr[16];
  __shared__ float lsv[2][16], ltl[16];
  __shared__ float fred[4];
  __shared__ int lastf;
  int t = threadIdx.x, lane = t & 63, w = t >> 6;
  int r0 = blockIdx.x * 16;
  int j = w * 64 + lane;
  const float4* mean4 = (const float4*)(ws + WS_MEANS);
  float4 mk[16];
#pragma unroll
  for (int q = 0; q < 16; ++q) mk[q] = mean4[j * 16 + q];
  const float4* c4 = (const float4*)(contr + (size_t)r0 * C_);
  float4* lc4 = (float4*)lc;
  lc4[t] = c4[t];
  lc4[t + 128] = c4[t + 128];
  __syncthreads();
  if (t < 16) {                    // 16 parallel per-row norms
    float ss = 0.0f;
#pragma unroll
    for (int q = 0; q < 16; ++q) {
      float4 v = lc4[t * 16 + q];
      ss += v.x * v.x + v.y * v.y + v.z * v.z + v.w * v.w;
    }
    invr[t] = 1.0f / fmaxf(sqrtf(ss), 1e-12f);
  }
  __syncthreads();
#pragma unroll 1
  for (int rg = 0; rg < 4; ++rg) { // 4 rows at a time: ILP without spill
    const float4* cr = lc4 + rg * 64;
    float a0 = 0.0f, a1 = 0.0f, a2 = 0.0f, a3 = 0.0f;
#pragma unroll
    for (int q = 0; q < 16; ++q) {
      float4 m = mk[q];
      float4 cc0 = cr[q], cc1 = cr[16 + q], cc2 = cr[32 + q], cc3 = cr[48 + q];
      a0 += cc0.x * m.x + cc0.y * m.y + cc0.z * m.z + cc0.w * m.w;
      a1 += cc1.x * m.x + cc1.y * m.y + cc1.z * m.z + cc1.w * m.w;
      a2 += cc2.x * m.x + cc2.y * m.y + cc2.z * m.z + cc2.w * m.w;
      a3 += cc3.x * m.x + cc3.y * m.y + cc3.z * m.z + cc3.w * m.w;
    }
    int rb = rg * 4;
    float l0 = a0 * invr[rb + 0];
    float l1 = a1 * invr[rb + 1];
    float l2 = a2 * invr[rb + 2];
    float l3 = a3 * invr[rb + 3];
    float s0 = __expf(l0), s1 = __expf(l1), s2 = __expf(l2), s3 = __expf(l3);
#pragma unroll
    for (int off = 32; off > 0; off >>= 1) {  // 4 interleaved reductions
      s0 += __shfl_xor(s0, off);
      s1 += __shfl_xor(s1, off);
      s2 += __shfl_xor(s2, off);
      s3 += __shfl_xor(s3, off);
    }
    int tg0 = labels[r0 + rb + 0], tg1 = labels[r0 + rb + 1];
    int tg2 = labels[r0 + rb + 2], tg3 = labels[r0 + rb + 3];
    float t0 = __shfl(l0, tg0), t1 = __shfl(l1, tg1);
    float t2 = __shfl(l2, tg2), t3 = __shfl(l3, tg3);
    if (lane == 0) {
      lsv[w][rb + 0] = s0; lsv[w][rb + 1] = s1;
      lsv[w][rb + 2] = s2; lsv[w][rb + 3] = s3;
      if (w == 0) { ltl[rb] = t0; ltl[rb + 1] = t1; ltl[rb + 2] = t2; ltl[rb + 3] = t3; }
    }
  }
  __syncthreads();
  if (t < 16) {
    float nll = __logf(lsv[0][t] + lsv[1][t]) - ltl[t];
#pragma unroll
    for (int off = 8; off > 0; off >>= 1) nll += __shfl_xor(nll, off);
    if (t == 0) atomicAdd(&ws[WS_NLL], nll);
  }
  // ---- last-block final combine (release/acquire via done-counter) ----
  __syncthreads();
  if (t == 0) {
    __threadfence();               // release: my nll add visible
    unsigned v = atomicAdd(&((unsigned*)ws)[WS_DONE], 1u);
    lastf = (v == 511u);
  }
  __syncthreads();
  if (lastf) {
    __threadfence();               // acquire: all blocks' adds visible
    float a = 0.0f, c = 0.0f;
    for (int i = t; i < 1024; i += 128) {
      a += ws[WS_APART + i * 2 + 0];
      c += ws[WS_APART + i * 2 + 1];
    }
#pragma unroll
    for (int off = 32; off > 0; off >>= 1) {
      a += __shfl_xor(a, off);
      c += __shfl_xor(c, off);
    }
    if (lane == 0) { fred[w * 2] = a; fred[w * 2 + 1] = c; }
    __syncthreads();
    if (t == 0) {
      float at = fred[0] + fred[2];
      float ct = fred[1] + fred[3];
      out[0] = at / ct + 10.0f * ws[WS_NLL] * (1.0f / (float)BN_);
    }
  }
}

extern "C" void kernel_launch(void* const* d_in, const int* in_sizes, int n_in,
                              void* d_out, int out_size, void* d_ws, size_t ws_size,
                              hipStream_t stream) {
  const float* emb    = (const float*)d_in[0];
  const float* contr  = (const float*)d_in[1];
  const float* absc   = (const float*)d_in[2];
  const int*   mask   = (const int*)d_in[3];
  const int*   labels = (const int*)d_in[4];
  float* ws  = (float*)d_ws;
  float* out = (float*)d_out;

  k_main<<<128 + 1024, 256, 0, stream>>>(emb, absc, contr, labels, mask, ws);
  k_logits_final<<<512, 128, 0, stream>>>(contr, labels, ws, out);
}